// Round 2
// baseline (6156.839 us; speedup 1.0000x reference)
//
#include <hip/hip_runtime.h>
#include <math.h>

#define B_ 256
#define T_ 576
#define FT_ 24
#define M_ 32
#define H_ 256
#define E_ 512
#define KX_ 544   // E + M
#define ND_ 2048  // 2*4H
#define EPS_ 1e-6f
#define LDAS 72   // 64 + 8 pad (shorts)
#define NBLK 256

typedef __attribute__((ext_vector_type(8))) short bf8;   // 8 bf16 (4 VGPRs)
typedef __attribute__((ext_vector_type(4))) float f4;

__device__ __forceinline__ float bf2f(unsigned short s) {
    union { unsigned u; float f; } c; c.u = ((unsigned)s) << 16; return c.f;
}
__device__ __forceinline__ short f2bf(float f) {
    union { float f; unsigned u; } c; c.f = f;
    unsigned r = c.u + 0x7fffu + ((c.u >> 16) & 1u);
    return (short)(r >> 16);
}
__device__ __forceinline__ float sigm(float x) { return 1.f / (1.f + expf(-x)); }

// sense-reversal grid barrier: bar[0]=arrive counter, bar[1]=generation
__device__ __forceinline__ void gbar(unsigned* bar) {
    __syncthreads();
    if (threadIdx.x == 0) {
        __threadfence();   // release: flush our writes device-wide (cross-XCD L2 wb)
        unsigned gen = __hip_atomic_load(&bar[1], __ATOMIC_RELAXED, __HIP_MEMORY_SCOPE_AGENT);
        unsigned a = __hip_atomic_fetch_add(&bar[0], 1u, __ATOMIC_ACQ_REL, __HIP_MEMORY_SCOPE_AGENT);
        if (a == NBLK - 1u) {
            __hip_atomic_store(&bar[0], 0u, __ATOMIC_RELAXED, __HIP_MEMORY_SCOPE_AGENT);
            __hip_atomic_fetch_add(&bar[1], 1u, __ATOMIC_RELEASE, __HIP_MEMORY_SCOPE_AGENT);
        } else {
            while (__hip_atomic_load(&bar[1], __ATOMIC_ACQUIRE, __HIP_MEMORY_SCOPE_AGENT) == gen)
                __builtin_amdgcn_s_sleep(2);
        }
        __threadfence();   // acquire: invalidate caches so we see others' writes
    }
    __syncthreads();
}

__device__ __forceinline__ void mfma4(const short (*As)[LDAS], const short (*Bs)[LDAS],
                                      int wm, int wn, int fr, int fk, f4 acc[2][2]) {
    bf8 a0 = *(const bf8*)&As[wm + fr][fk];
    bf8 a1 = *(const bf8*)&As[wm + 16 + fr][fk];
    bf8 b0 = *(const bf8*)&Bs[wn + fr][fk];
    bf8 b1 = *(const bf8*)&Bs[wn + 16 + fr][fk];
    acc[0][0] = __builtin_amdgcn_mfma_f32_16x16x32_bf16(a0, b0, acc[0][0], 0, 0, 0);
    acc[0][1] = __builtin_amdgcn_mfma_f32_16x16x32_bf16(a0, b1, acc[0][1], 0, 0, 0);
    acc[1][0] = __builtin_amdgcn_mfma_f32_16x16x32_bf16(a1, b0, acc[1][0], 0, 0, 0);
    acc[1][1] = __builtin_amdgcn_mfma_f32_16x16x32_bf16(a1, b1, acc[1][1], 0, 0, 0);
}

// 64x64 output tile GEMM, BK=64 (tail 32 ok): acc += A[64xK] * Wt[64xK]^T
__device__ __forceinline__ void gemm64(const short* __restrict__ A, int lda,
                                       const short* __restrict__ Wt, int ldw, int K,
                                       short (*As)[LDAS], short (*Bs)[LDAS], int tid,
                                       f4 acc[2][2]) {
    int lane = tid & 63, w = tid >> 6;
    int wm = (w & 1) * 32, wn = (w >> 1) * 32;
    int fr = lane & 15, fk = (lane >> 4) * 8;
    int r = tid >> 2, c0 = (tid & 3) * 16, c8 = (tid & 3) * 8;
    int4 pa0, pa1, pb0, pb1;
    auto ld = [&](int k0) {
        if (K - k0 >= 64) {
            pa0 = *(const int4*)(A + r * lda + k0 + c0);
            pa1 = *(const int4*)(A + r * lda + k0 + c0 + 8);
            pb0 = *(const int4*)(Wt + r * ldw + k0 + c0);
            pb1 = *(const int4*)(Wt + r * ldw + k0 + c0 + 8);
        } else {
            pa0 = *(const int4*)(A + r * lda + k0 + c8);
            pb0 = *(const int4*)(Wt + r * ldw + k0 + c8);
        }
    };
    ld(0);
    for (int k0 = 0; k0 < K; k0 += 64) {
        int rem = K - k0;
        if (rem >= 64) {
            *(int4*)&As[r][c0] = pa0; *(int4*)&As[r][c0 + 8] = pa1;
            *(int4*)&Bs[r][c0] = pb0; *(int4*)&Bs[r][c0 + 8] = pb1;
        } else {
            *(int4*)&As[r][c8] = pa0;
            *(int4*)&Bs[r][c8] = pb0;
        }
        __syncthreads();
        if (k0 + 64 < K) ld(k0 + 64);
        mfma4(As, Bs, wm, wn, fr, fk, acc);
        if (rem >= 64) mfma4(As, Bs, wm, wn, fr, fk + 32, acc);
        __syncthreads();
    }
}

// ---------------- fused setup: casts, gate-permuted weights, bias, alpha, init ----------------
struct SetupPrm {
    const float *enc, *fhist, *ff, *hidden, *cell;
    const float *aW1, *aW2, *Wih, *Whh, *bih, *bhh, *fW1;
    short *W1b, *W2b, *Wihb, *Whhb, *fW1b, *encb, *xb, *hA;
    float *bcomb, *alpha, *cbuf;
    unsigned *bar;
};

__global__ __launch_bounds__(256) void k_setup(SetupPrm p) {
    const int NT = 2048 * 256;
    int gt = blockIdx.x * 256 + threadIdx.x;
    if (gt == 0) { p.bar[0] = 0; p.bar[1] = 0; }
    auto cast = [&](const float* s, short* d, int n4) {
        for (int i = gt; i < n4; i += NT) {
            float4 v = ((const float4*)s)[i];
            short4 o; o.x = f2bf(v.x); o.y = f2bf(v.y); o.z = f2bf(v.z); o.w = f2bf(v.w);
            ((short4*)d)[i] = o;
        }
    };
    cast(p.aW1, p.W1b, T_ * KX_ / 4);
    cast(p.aW2, p.W2b, T_ * T_ / 4);
    cast(p.fW1, p.fW1b, H_ * E_ / 4);
    cast(p.enc, p.encb, B_ * T_ * E_ / 4);
    // gate-permuted Wih: new row d*1024 + j*4 + g  <-  orig d*1024 + g*256 + j
    for (int i = gt; i < ND_ * KX_ / 4; i += NT) {
        int row = i / (KX_ / 4), c4 = i % (KX_ / 4);
        int d = row >> 10, rest = row & 1023, j = rest >> 2, g = rest & 3;
        int orig = d * 1024 + g * 256 + j;
        float4 v = ((const float4*)(p.Wih + orig * KX_))[c4];
        short4 o; o.x = f2bf(v.x); o.y = f2bf(v.y); o.z = f2bf(v.z); o.w = f2bf(v.w);
        ((short4*)(p.Wihb + row * KX_))[c4] = o;
    }
    for (int i = gt; i < ND_ * H_ / 4; i += NT) {
        int row = i / (H_ / 4), c4 = i % (H_ / 4);
        int d = row >> 10, rest = row & 1023, j = rest >> 2, g = rest & 3;
        int orig = d * 1024 + g * 256 + j;
        float4 v = ((const float4*)(p.Whh + orig * H_))[c4];
        short4 o; o.x = f2bf(v.x); o.y = f2bf(v.y); o.z = f2bf(v.z); o.w = f2bf(v.w);
        ((short4*)(p.Whhb + row * H_))[c4] = o;
    }
    for (int i = gt; i < ND_; i += NT) {
        int d = i >> 10, rest = i & 1023, j = rest >> 2, g = rest & 3;
        int orig = d * 1024 + g * 256 + j;
        p.bcomb[i] = p.bih[orig] + p.bhh[orig];
    }
    // init: x0 = [h0|h1|ff0] bf16, hA = h0 bf16, c fp32
    for (int i = gt; i < 2 * B_ * H_; i += NT) {
        int d = i >> 16, b = (i >> 8) & 255, j = i & 255;
        short hv = f2bf(p.hidden[i]);
        p.xb[b * KX_ + d * H_ + j] = hv;
        p.hA[i] = hv;                       // layout [d][b][j] == flat i
        p.cbuf[i] = p.cell[i];
        if (d == 0 && j < M_) p.xb[b * KX_ + E_ + j] = f2bf(p.ff[b * FT_ * M_ + j]);
    }
    // alpha softmax (one wave per batch, blocks 0..255)
    if (blockIdx.x < 256 && threadIdx.x < 64) {
        int b = blockIdx.x, t = threadIdx.x;
        float dp = 0.f;
        if (t < 24) {
            float fv[M_];
            const float* fp = p.ff + (b * FT_ + t) * M_;
            #pragma unroll
            for (int m = 0; m < M_; m++) fv[m] = fp[m];
            float dist = 0.f;
            for (int pp = 0; pp < 24; pp++) {
                const float* hp = p.fhist + (b * T_ + pp * 24 + t) * M_;
                float s = 0.f;
                #pragma unroll
                for (int m = 0; m < M_; m++) { float d = fv[m] - hp[m] + EPS_; s += d * d; }
                dist += sqrtf(s);
            }
            dp = 1.f / dist;
        }
        float v = (t < 24) ? dp : -INFINITY;
        float mx = v;
        for (int off = 32; off; off >>= 1) mx = fmaxf(mx, __shfl_xor(mx, off));
        float e = (t < 24) ? expf(dp - mx) : 0.f;
        float sme = e;
        for (int off = 32; off; off >>= 1) sme += __shfl_xor(sme, off);
        if (t < 24) p.alpha[b * 24 + t] = e / sme;
    }
}

// ---------------- persistent loop kernel (plain launch + manual grid barrier) ----------------
struct LoopPrm {
    short *xb;
    const short *W1b, *W2b, *Wihb, *Whhb, *fW1b, *encb;
    const float *ab1, *ab2, *fb1, *fW2, *fb2, *ff;
    const float *bcomb, *alpha;
    short *s1;
    float *logit, *ctxp, *cbuf;
    short *hA, *hB;
    float *out;
    unsigned *bar;
};

__device__ __forceinline__ void fc_tile(const LoopPrm& p, int m0, int n0, int step,
                                        short (*As)[LDAS], short (*Bs)[LDAS],
                                        float* ypart, int tid) {
    f4 acc[2][2] = {};
    gemm64(p.xb + m0 * KX_, KX_, p.fW1b + n0 * E_, E_, E_, As, Bs, tid, acc);
    if (tid < 64) ypart[tid] = 0.f;
    __syncthreads();
    int lane = tid & 63, w = tid >> 6;
    int wm = (w & 1) * 32, wn = (w >> 1) * 32;
    int colb = n0 + wn + (lane & 15);
    int rloc = wm + (lane >> 4) * 4;
    #pragma unroll
    for (int im = 0; im < 2; im++)
        #pragma unroll
        for (int q = 0; q < 4; q++) {
            float s = 0.f;
            #pragma unroll
            for (int in = 0; in < 2; in++) {
                int col = colb + in * 16;
                s += fmaxf(acc[im][in][q] + p.fb1[col], 0.f) * p.fW2[col];
            }
            #pragma unroll
            for (int off = 1; off < 16; off <<= 1) s += __shfl_xor(s, off);
            if ((lane & 15) == 0) atomicAdd(&ypart[rloc + im * 16 + q], s);
        }
    __syncthreads();
    if (tid < 64) atomicAdd(&p.out[(m0 + tid) * FT_ + step], ypart[tid]);
}

__global__ __launch_bounds__(256) void k_loop(LoopPrm p) {
    __shared__ union {
        struct { short As[64][LDAS]; short Bs[64][LDAS]; float ypart[64]; } g;
        struct { float wt[T_]; float red4[4]; float red[4][512]; } c;
        float gt[64][68];
    } sm;
    const int blk = blockIdx.x, tid = threadIdx.x;
    const int lane = tid & 63, w = tid >> 6;
    const int wm = (w & 1) * 32, wn = (w >> 1) * 32;

    for (int t = 0; t < FT_; t++) {
        // ---- phase A: attn1 (36 tiles) + fc of previous step (16 tiles) ----
        if (blk < 36) {
            int m0 = (blk / 9) * 64, n0 = (blk % 9) * 64;
            f4 acc[2][2] = {};
            gemm64(p.xb + m0 * KX_, KX_, p.W1b + n0 * KX_, KX_, KX_,
                   sm.g.As, sm.g.Bs, tid, acc);
            int colb = n0 + wn + (lane & 15);
            int rowb = m0 + wm + (lane >> 4) * 4;
            #pragma unroll
            for (int im = 0; im < 2; im++)
                #pragma unroll
                for (int in = 0; in < 2; in++) {
                    int col = colb + in * 16;
                    float bv = p.ab1[col];
                    #pragma unroll
                    for (int q = 0; q < 4; q++)
                        p.s1[(rowb + im * 16 + q) * T_ + col] =
                            f2bf(tanhf(acc[im][in][q] + bv));
                }
        } else if (blk < 52 && t > 0) {
            int u = blk - 36;
            fc_tile(p, (u >> 2) * 64, (u & 3) * 64, t - 1,
                    sm.g.As, sm.g.Bs, sm.g.ypart, tid);
        }
        gbar(p.bar);

        // ---- phase B: attn2 -> fp32 logits (36 tiles) ----
        if (blk < 36) {
            int m0 = (blk / 9) * 64, n0 = (blk % 9) * 64;
            f4 acc[2][2] = {};
            gemm64(p.s1 + m0 * T_, T_, p.W2b + n0 * T_, T_, T_,
                   sm.g.As, sm.g.Bs, tid, acc);
            int colb = n0 + wn + (lane & 15);
            int rowb = m0 + wm + (lane >> 4) * 4;
            #pragma unroll
            for (int im = 0; im < 2; im++)
                #pragma unroll
                for (int in = 0; in < 2; in++) {
                    int col = colb + in * 16;
                    float bv = p.ab2[col];
                    #pragma unroll
                    for (int q = 0; q < 4; q++)
                        p.logit[(rowb + im * 16 + q) * T_ + col] = acc[im][in][q] + bv;
                }
        }
        gbar(p.bar);

        // ---- phase C: softmax*alpha + weighted enc sum (1 block per batch) ----
        {
            int b = blk;
            const float* lg = p.logit + b * T_;
            float l0 = lg[tid], l1 = lg[tid + 256];
            float l2 = (tid < 64) ? lg[tid + 512] : -INFINITY;
            float mx = fmaxf(fmaxf(l0, l1), l2);
            for (int off = 32; off; off >>= 1) mx = fmaxf(mx, __shfl_xor(mx, off));
            if (lane == 0) sm.c.red4[w] = mx;
            __syncthreads();
            mx = fmaxf(fmaxf(sm.c.red4[0], sm.c.red4[1]),
                       fmaxf(sm.c.red4[2], sm.c.red4[3]));
            float e0 = expf(l0 - mx), e1 = expf(l1 - mx);
            float e2 = (tid < 64) ? expf(l2 - mx) : 0.f;
            float sme = e0 + e1 + e2;
            for (int off = 32; off; off >>= 1) sme += __shfl_xor(sme, off);
            __syncthreads();
            if (lane == 0) sm.c.red4[w] = sme;
            __syncthreads();
            float inv = 1.f / (sm.c.red4[0] + sm.c.red4[1] + sm.c.red4[2] + sm.c.red4[3]);
            const float* al = p.alpha + b * 24;
            sm.c.wt[tid]       = e0 * inv * al[tid / 24];
            sm.c.wt[tid + 256] = e1 * inv * al[(tid + 256) / 24];
            if (tid < 64) sm.c.wt[tid + 512] = e2 * inv * al[(tid + 512) / 24];
            __syncthreads();
            // accumulate: oct = 8 channels per thread, rp = row phase (4)
            int oct = tid & 63, rp = tid >> 6;
            const short* ebase = p.encb + (size_t)b * T_ * E_ + oct * 8;
            float a0 = 0.f, a1 = 0.f, a2 = 0.f, a3 = 0.f;
            float a4 = 0.f, a5 = 0.f, a6 = 0.f, a7 = 0.f;
            #pragma unroll 4
            for (int r = rp; r < T_; r += 4) {
                float wv = sm.c.wt[r];
                int4 v = *(const int4*)(ebase + (size_t)r * E_);
                a0 += wv * bf2f((unsigned short)v.x);
                a1 += wv * bf2f((unsigned short)(((unsigned)v.x) >> 16));
                a2 += wv * bf2f((unsigned short)v.y);
                a3 += wv * bf2f((unsigned short)(((unsigned)v.y) >> 16));
                a4 += wv * bf2f((unsigned short)v.z);
                a5 += wv * bf2f((unsigned short)(((unsigned)v.z) >> 16));
                a6 += wv * bf2f((unsigned short)v.w);
                a7 += wv * bf2f((unsigned short)(((unsigned)v.w) >> 16));
            }
            float* rr = &sm.c.red[rp][oct * 8];
            rr[0] = a0; rr[1] = a1; rr[2] = a2; rr[3] = a3;
            rr[4] = a4; rr[5] = a5; rr[6] = a6; rr[7] = a7;
            __syncthreads();
            float s0 = 0.f, s1v = 0.f;
            #pragma unroll
            for (int q = 0; q < 4; q++) {
                s0  += sm.c.red[q][tid * 2];
                s1v += sm.c.red[q][tid * 2 + 1];
            }
            p.ctxp[b * E_ + tid * 2]     = s0;
            p.ctxp[b * E_ + tid * 2 + 1] = s1v;
        }
        gbar(p.bar);

        // ---- phase D: gates GEMM + fused LSTM pointwise (128 tiles) ----
        if (blk < 128) {
            int n0 = (blk & 31) * 64, m0 = (blk >> 5) * 64;
            int fr = lane & 15, fk = (lane >> 4) * 8;
            int r = tid >> 2, c0 = (tid & 3) * 16, c8 = (tid & 3) * 8;
            f4 acc[2][2] = {};
            // phase 1: inp = [ctx | ff_t], K = 544
            for (int k0 = 0; k0 < KX_; k0 += 64) {
                int rem = KX_ - k0;
                if (rem >= 64) {
                    const float* cp = p.ctxp + (m0 + r) * E_ + k0 + c0;
                    short av[16];
                    #pragma unroll
                    for (int i = 0; i < 16; i++) av[i] = f2bf(cp[i]);
                    *(int4*)&sm.g.As[r][c0]     = *(int4*)&av[0];
                    *(int4*)&sm.g.As[r][c0 + 8] = *(int4*)&av[8];
                    *(int4*)&sm.g.Bs[r][c0]     = *(const int4*)(p.Wihb + (n0 + r) * KX_ + k0 + c0);
                    *(int4*)&sm.g.Bs[r][c0 + 8] = *(const int4*)(p.Wihb + (n0 + r) * KX_ + k0 + c0 + 8);
                } else {
                    const float* fp = p.ff + ((m0 + r) * FT_ + t) * M_ + (k0 + c8 - E_);
                    short av[8];
                    #pragma unroll
                    for (int i = 0; i < 8; i++) av[i] = f2bf(fp[i]);
                    *(int4*)&sm.g.As[r][c8] = *(int4*)&av[0];
                    *(int4*)&sm.g.Bs[r][c8] = *(const int4*)(p.Wihb + (n0 + r) * KX_ + k0 + c8);
                }
                __syncthreads();
                mfma4(sm.g.As, sm.g.Bs, wm, wn, fr, fk, acc);
                if (rem >= 64) mfma4(sm.g.As, sm.g.Bs, wm, wn, fr, fk + 32, acc);
                __syncthreads();
            }
            // phase 2: + h_{t-1}[d] * Whh^T, K = 256
            int d = n0 >> 10;
            const short* hprev = (t & 1) ? p.hB : p.hA;
            short* hnext       = (t & 1) ? p.hA : p.hB;
            gemm64(hprev + d * B_ * H_ + m0 * H_, H_, p.Whhb + n0 * H_, H_, H_,
                   sm.g.As, sm.g.Bs, tid, acc);
            // epilogue: +bias -> LDS, then LSTM pointwise
            int clb = wn + (lane & 15);
            int rlb = wm + (lane >> 4) * 4;
            #pragma unroll
            for (int im = 0; im < 2; im++)
                #pragma unroll
                for (int in = 0; in < 2; in++) {
                    int cl = clb + in * 16;
                    float bv = p.bcomb[n0 + cl];
                    #pragma unroll
                    for (int q = 0; q < 4; q++)
                        sm.gt[rlb + im * 16 + q][cl] = acc[im][in][q] + bv;
                }
            __syncthreads();
            int j0 = (n0 >> 2) & 255;
            #pragma unroll
            for (int it = 0; it < 4; it++) {
                int item = tid + it * 256;
                int rl = item >> 4, ql = item & 15;
                float ig = sm.gt[rl][ql * 4 + 0];
                float fg = sm.gt[rl][ql * 4 + 1];
                float gg = sm.gt[rl][ql * 4 + 2];
                float og = sm.gt[rl][ql * 4 + 3];
                int b = m0 + rl, j = j0 + ql;
                int ci = d * 65536 + b * 256 + j;
                float cn = sigm(fg) * p.cbuf[ci] + sigm(ig) * tanhf(gg);
                float hn = sigm(og) * tanhf(cn);
                p.cbuf[ci] = cn;
                short hv = f2bf(hn);
                p.xb[b * KX_ + d * H_ + j] = hv;
                hnext[ci] = hv;
                if (d == 0 && j < M_ && t + 1 < FT_)
                    p.xb[b * KX_ + E_ + j] = f2bf(p.ff[(b * FT_ + t + 1) * M_ + j]);
                if (n0 == 0 && ql == 0) p.out[b * FT_ + t] = p.fb2[0];
            }
        }
        gbar(p.bar);
    }
    // tail fc for the last step
    if (blk < 16)
        fc_tile(p, (blk >> 2) * 64, (blk & 3) * 64, FT_ - 1,
                sm.g.As, sm.g.Bs, sm.g.ypart, tid);
}

extern "C" void kernel_launch(void* const* d_in, const int* in_sizes, int n_in,
                              void* d_out, int out_size, void* d_ws, size_t ws_size,
                              hipStream_t stream) {
    (void)in_sizes; (void)n_in; (void)out_size; (void)ws_size;
    const float* enc_f  = (const float*)d_in[0];
    const float* fhist  = (const float*)d_in[1];
    const float* ff     = (const float*)d_in[3];
    const float* hidden = (const float*)d_in[4];
    const float* cell   = (const float*)d_in[5];
    const float* aW1    = (const float*)d_in[6];
    const float* ab1    = (const float*)d_in[7];
    const float* aW2    = (const float*)d_in[8];
    const float* ab2    = (const float*)d_in[9];
    const float* Wih    = (const float*)d_in[10];
    const float* Whh    = (const float*)d_in[11];
    const float* bih    = (const float*)d_in[12];
    const float* bhh    = (const float*)d_in[13];
    const float* fW1    = (const float*)d_in[14];
    const float* fb1    = (const float*)d_in[15];
    const float* fW2    = (const float*)d_in[16];
    const float* fb2    = (const float*)d_in[17];
    float* out = (float*)d_out;

    char* pws = (char*)d_ws;
    auto take = [&](size_t n) { char* r = pws; pws += (n + 255) & ~(size_t)255; return r; };
    unsigned* bar = (unsigned*)take(256);
    float* alpha = (float*)take(B_ * 24 * 4);
    short* xb    = (short*)take(B_ * KX_ * 2);
    short* hA    = (short*)take(2 * B_ * H_ * 2);
    short* hB    = (short*)take(2 * B_ * H_ * 2);
    float* cbuf  = (float*)take(2 * B_ * H_ * 4);
    short* s1    = (short*)take(B_ * T_ * 2);
    float* logit = (float*)take(B_ * T_ * 4);
    float* ctxp  = (float*)take(B_ * E_ * 4);
    float* bcomb = (float*)take(ND_ * 4);
    short* W1b   = (short*)take(T_ * KX_ * 2);
    short* W2b   = (short*)take(T_ * T_ * 2);
    short* Wihb  = (short*)take(ND_ * KX_ * 2);
    short* Whhb  = (short*)take(ND_ * H_ * 2);
    short* fW1b  = (short*)take(H_ * E_ * 2);
    short* encb  = (short*)take((size_t)B_ * T_ * E_ * 2);

    SetupPrm sp;
    sp.enc = enc_f; sp.fhist = fhist; sp.ff = ff; sp.hidden = hidden; sp.cell = cell;
    sp.aW1 = aW1; sp.aW2 = aW2; sp.Wih = Wih; sp.Whh = Whh; sp.bih = bih; sp.bhh = bhh;
    sp.fW1 = fW1;
    sp.W1b = W1b; sp.W2b = W2b; sp.Wihb = Wihb; sp.Whhb = Whhb; sp.fW1b = fW1b;
    sp.encb = encb; sp.xb = xb; sp.hA = hA;
    sp.bcomb = bcomb; sp.alpha = alpha; sp.cbuf = cbuf;
    sp.bar = bar;

    k_setup<<<2048, 256, 0, stream>>>(sp);

    LoopPrm lp;
    lp.xb = xb;
    lp.W1b = W1b; lp.W2b = W2b; lp.Wihb = Wihb; lp.Whhb = Whhb; lp.fW1b = fW1b;
    lp.encb = encb;
    lp.ab1 = ab1; lp.ab2 = ab2; lp.fb1 = fb1; lp.fW2 = fW2; lp.fb2 = fb2; lp.ff = ff;
    lp.bcomb = bcomb; lp.alpha = alpha;
    lp.s1 = s1; lp.logit = logit; lp.ctxp = ctxp; lp.cbuf = cbuf;
    lp.hA = hA; lp.hB = hB;
    lp.out = out;
    lp.bar = bar;

    k_loop<<<NBLK, 256, 0, stream>>>(lp);
}

// Round 3
// 4147.462 us; speedup vs baseline: 1.4845x; 1.4845x over previous
//
#include <hip/hip_runtime.h>
#include <math.h>

#define B_ 256
#define T_ 576
#define FT_ 24
#define M_ 32
#define H_ 256
#define E_ 512
#define KX_ 544   // E + M
#define ND_ 2048  // 2*4H
#define EPS_ 1e-6f
#define LDAS 72   // 64 + 8 pad (shorts)
#define NBLK 256

typedef __attribute__((ext_vector_type(8))) short bf8;   // 8 bf16 (4 VGPRs)
typedef __attribute__((ext_vector_type(4))) float f4;

__device__ __forceinline__ float bf2f(unsigned short s) {
    union { unsigned u; float f; } c; c.u = ((unsigned)s) << 16; return c.f;
}
__device__ __forceinline__ short f2bf(float f) {
    union { float f; unsigned u; } c; c.f = f;
    unsigned r = c.u + 0x7fffu + ((c.u >> 16) & 1u);
    return (short)(r >> 16);
}
__device__ __forceinline__ float sigm(float x) { return 1.f / (1.f + expf(-x)); }

// sense-reversal grid barrier: bar[0]=arrive counter, bar[1]=generation.
// CRITICAL: the poll load is RELAXED (an agent-scope ACQUIRE load emits
// buffer_inv sc1 = full L1+L2 invalidate PER POLL -> cache thrash storm).
// One acquire fence after spin-exit provides the needed ordering.
__device__ __forceinline__ void gbar(unsigned* bar, bool wrote) {
    __syncthreads();
    if (threadIdx.x == 0) {
        if (wrote) __threadfence();   // release: L2 writeback so other XCDs see our data
        unsigned gen = __hip_atomic_load(&bar[1], __ATOMIC_RELAXED, __HIP_MEMORY_SCOPE_AGENT);
        unsigned a = __hip_atomic_fetch_add(&bar[0], 1u, __ATOMIC_RELEASE, __HIP_MEMORY_SCOPE_AGENT);
        if (a == NBLK - 1u) {
            __hip_atomic_store(&bar[0], 0u, __ATOMIC_RELAXED, __HIP_MEMORY_SCOPE_AGENT);
            __hip_atomic_store(&bar[1], gen + 1u, __ATOMIC_RELEASE, __HIP_MEMORY_SCOPE_AGENT);
        } else {
            while (__hip_atomic_load(&bar[1], __ATOMIC_RELAXED, __HIP_MEMORY_SCOPE_AGENT) == gen)
                __builtin_amdgcn_s_sleep(8);
        }
        __threadfence();   // acquire: one-time cache invalidate so we see others' writes
    }
    __syncthreads();
}

__device__ __forceinline__ void mfma4(const short (*As)[LDAS], const short (*Bs)[LDAS],
                                      int wm, int wn, int fr, int fk, f4 acc[2][2]) {
    bf8 a0 = *(const bf8*)&As[wm + fr][fk];
    bf8 a1 = *(const bf8*)&As[wm + 16 + fr][fk];
    bf8 b0 = *(const bf8*)&Bs[wn + fr][fk];
    bf8 b1 = *(const bf8*)&Bs[wn + 16 + fr][fk];
    acc[0][0] = __builtin_amdgcn_mfma_f32_16x16x32_bf16(a0, b0, acc[0][0], 0, 0, 0);
    acc[0][1] = __builtin_amdgcn_mfma_f32_16x16x32_bf16(a0, b1, acc[0][1], 0, 0, 0);
    acc[1][0] = __builtin_amdgcn_mfma_f32_16x16x32_bf16(a1, b0, acc[1][0], 0, 0, 0);
    acc[1][1] = __builtin_amdgcn_mfma_f32_16x16x32_bf16(a1, b1, acc[1][1], 0, 0, 0);
}

// 64x64 output tile GEMM, BK=64 (tail 32 ok): acc += A[64xK] * Wt[64xK]^T
__device__ __forceinline__ void gemm64(const short* __restrict__ A, int lda,
                                       const short* __restrict__ Wt, int ldw, int K,
                                       short (*As)[LDAS], short (*Bs)[LDAS], int tid,
                                       f4 acc[2][2]) {
    int lane = tid & 63, w = tid >> 6;
    int wm = (w & 1) * 32, wn = (w >> 1) * 32;
    int fr = lane & 15, fk = (lane >> 4) * 8;
    int r = tid >> 2, c0 = (tid & 3) * 16, c8 = (tid & 3) * 8;
    int4 pa0, pa1, pb0, pb1;
    auto ld = [&](int k0) {
        if (K - k0 >= 64) {
            pa0 = *(const int4*)(A + r * lda + k0 + c0);
            pa1 = *(const int4*)(A + r * lda + k0 + c0 + 8);
            pb0 = *(const int4*)(Wt + r * ldw + k0 + c0);
            pb1 = *(const int4*)(Wt + r * ldw + k0 + c0 + 8);
        } else {
            pa0 = *(const int4*)(A + r * lda + k0 + c8);
            pb0 = *(const int4*)(Wt + r * ldw + k0 + c8);
        }
    };
    ld(0);
    for (int k0 = 0; k0 < K; k0 += 64) {
        int rem = K - k0;
        if (rem >= 64) {
            *(int4*)&As[r][c0] = pa0; *(int4*)&As[r][c0 + 8] = pa1;
            *(int4*)&Bs[r][c0] = pb0; *(int4*)&Bs[r][c0 + 8] = pb1;
        } else {
            *(int4*)&As[r][c8] = pa0;
            *(int4*)&Bs[r][c8] = pb0;
        }
        __syncthreads();
        if (k0 + 64 < K) ld(k0 + 64);
        mfma4(As, Bs, wm, wn, fr, fk, acc);
        if (rem >= 64) mfma4(As, Bs, wm, wn, fr, fk + 32, acc);
        __syncthreads();
    }
}

// ---------------- fused setup: casts, gate-permuted weights, bias, alpha, init ----------------
struct SetupPrm {
    const float *enc, *fhist, *ff, *hidden, *cell;
    const float *aW1, *aW2, *Wih, *Whh, *bih, *bhh, *fW1;
    short *W1b, *W2b, *Wihb, *Whhb, *fW1b, *encb, *xb, *hA;
    float *bcomb, *alpha, *cbuf;
    unsigned *bar;
};

__global__ __launch_bounds__(256) void k_setup(SetupPrm p) {
    const int NT = 2048 * 256;
    int gt = blockIdx.x * 256 + threadIdx.x;
    if (gt == 0) { p.bar[0] = 0; p.bar[1] = 0; }
    auto cast = [&](const float* s, short* d, int n4) {
        for (int i = gt; i < n4; i += NT) {
            float4 v = ((const float4*)s)[i];
            short4 o; o.x = f2bf(v.x); o.y = f2bf(v.y); o.z = f2bf(v.z); o.w = f2bf(v.w);
            ((short4*)d)[i] = o;
        }
    };
    cast(p.aW1, p.W1b, T_ * KX_ / 4);
    cast(p.aW2, p.W2b, T_ * T_ / 4);
    cast(p.fW1, p.fW1b, H_ * E_ / 4);
    cast(p.enc, p.encb, B_ * T_ * E_ / 4);
    // gate-permuted Wih: new row d*1024 + j*4 + g  <-  orig d*1024 + g*256 + j
    for (int i = gt; i < ND_ * KX_ / 4; i += NT) {
        int row = i / (KX_ / 4), c4 = i % (KX_ / 4);
        int d = row >> 10, rest = row & 1023, j = rest >> 2, g = rest & 3;
        int orig = d * 1024 + g * 256 + j;
        float4 v = ((const float4*)(p.Wih + orig * KX_))[c4];
        short4 o; o.x = f2bf(v.x); o.y = f2bf(v.y); o.z = f2bf(v.z); o.w = f2bf(v.w);
        ((short4*)(p.Wihb + row * KX_))[c4] = o;
    }
    for (int i = gt; i < ND_ * H_ / 4; i += NT) {
        int row = i / (H_ / 4), c4 = i % (H_ / 4);
        int d = row >> 10, rest = row & 1023, j = rest >> 2, g = rest & 3;
        int orig = d * 1024 + g * 256 + j;
        float4 v = ((const float4*)(p.Whh + orig * H_))[c4];
        short4 o; o.x = f2bf(v.x); o.y = f2bf(v.y); o.z = f2bf(v.z); o.w = f2bf(v.w);
        ((short4*)(p.Whhb + row * H_))[c4] = o;
    }
    for (int i = gt; i < ND_; i += NT) {
        int d = i >> 10, rest = i & 1023, j = rest >> 2, g = rest & 3;
        int orig = d * 1024 + g * 256 + j;
        p.bcomb[i] = p.bih[orig] + p.bhh[orig];
    }
    // init: x0 = [h0|h1|ff0] bf16, hA = h0 bf16, c fp32
    for (int i = gt; i < 2 * B_ * H_; i += NT) {
        int d = i >> 16, b = (i >> 8) & 255, j = i & 255;
        short hv = f2bf(p.hidden[i]);
        p.xb[b * KX_ + d * H_ + j] = hv;
        p.hA[i] = hv;                       // layout [d][b][j] == flat i
        p.cbuf[i] = p.cell[i];
        if (d == 0 && j < M_) p.xb[b * KX_ + E_ + j] = f2bf(p.ff[b * FT_ * M_ + j]);
    }
    // alpha softmax (one wave per batch, blocks 0..255)
    if (blockIdx.x < 256 && threadIdx.x < 64) {
        int b = blockIdx.x, t = threadIdx.x;
        float dp = 0.f;
        if (t < 24) {
            float fv[M_];
            const float* fp = p.ff + (b * FT_ + t) * M_;
            #pragma unroll
            for (int m = 0; m < M_; m++) fv[m] = fp[m];
            float dist = 0.f;
            for (int pp = 0; pp < 24; pp++) {
                const float* hp = p.fhist + (b * T_ + pp * 24 + t) * M_;
                float s = 0.f;
                #pragma unroll
                for (int m = 0; m < M_; m++) { float d = fv[m] - hp[m] + EPS_; s += d * d; }
                dist += sqrtf(s);
            }
            dp = 1.f / dist;
        }
        float v = (t < 24) ? dp : -INFINITY;
        float mx = v;
        for (int off = 32; off; off >>= 1) mx = fmaxf(mx, __shfl_xor(mx, off));
        float e = (t < 24) ? expf(dp - mx) : 0.f;
        float sme = e;
        for (int off = 32; off; off >>= 1) sme += __shfl_xor(sme, off);
        if (t < 24) p.alpha[b * 24 + t] = e / sme;
    }
}

// ---------------- persistent loop kernel (plain launch + manual grid barrier) ----------------
struct LoopPrm {
    short *xb;
    const short *W1b, *W2b, *Wihb, *Whhb, *fW1b, *encb;
    const float *ab1, *ab2, *fb1, *fW2, *fb2, *ff;
    const float *bcomb, *alpha;
    short *s1;
    float *logit, *ctxp, *cbuf;
    short *hA, *hB;
    float *out;
    unsigned *bar;
};

__device__ __forceinline__ void fc_tile(const LoopPrm& p, int m0, int n0, int step,
                                        short (*As)[LDAS], short (*Bs)[LDAS],
                                        float* ypart, int tid) {
    f4 acc[2][2] = {};
    gemm64(p.xb + m0 * KX_, KX_, p.fW1b + n0 * E_, E_, E_, As, Bs, tid, acc);
    if (tid < 64) ypart[tid] = 0.f;
    __syncthreads();
    int lane = tid & 63, w = tid >> 6;
    int wm = (w & 1) * 32, wn = (w >> 1) * 32;
    int colb = n0 + wn + (lane & 15);
    int rloc = wm + (lane >> 4) * 4;
    #pragma unroll
    for (int im = 0; im < 2; im++)
        #pragma unroll
        for (int q = 0; q < 4; q++) {
            float s = 0.f;
            #pragma unroll
            for (int in = 0; in < 2; in++) {
                int col = colb + in * 16;
                s += fmaxf(acc[im][in][q] + p.fb1[col], 0.f) * p.fW2[col];
            }
            #pragma unroll
            for (int off = 1; off < 16; off <<= 1) s += __shfl_xor(s, off);
            if ((lane & 15) == 0) atomicAdd(&ypart[rloc + im * 16 + q], s);
        }
    __syncthreads();
    if (tid < 64) atomicAdd(&p.out[(m0 + tid) * FT_ + step], ypart[tid]);
}

__global__ __launch_bounds__(256) void k_loop(LoopPrm p) {
    __shared__ union {
        struct { short As[64][LDAS]; short Bs[64][LDAS]; float ypart[64]; } g;
        struct { float wt[T_]; float red4[4]; float red[4][512]; } c;
        float gt[64][68];
    } sm;
    const int blk = blockIdx.x, tid = threadIdx.x;
    const int lane = tid & 63, w = tid >> 6;
    const int wm = (w & 1) * 32, wn = (w >> 1) * 32;

    for (int t = 0; t < FT_; t++) {
        // ---- phase A: attn1 (36 tiles) + fc of previous step (16 tiles) ----
        if (blk < 36) {
            int m0 = (blk / 9) * 64, n0 = (blk % 9) * 64;
            f4 acc[2][2] = {};
            gemm64(p.xb + m0 * KX_, KX_, p.W1b + n0 * KX_, KX_, KX_,
                   sm.g.As, sm.g.Bs, tid, acc);
            int colb = n0 + wn + (lane & 15);
            int rowb = m0 + wm + (lane >> 4) * 4;
            #pragma unroll
            for (int im = 0; im < 2; im++)
                #pragma unroll
                for (int in = 0; in < 2; in++) {
                    int col = colb + in * 16;
                    float bv = p.ab1[col];
                    #pragma unroll
                    for (int q = 0; q < 4; q++)
                        p.s1[(rowb + im * 16 + q) * T_ + col] =
                            f2bf(tanhf(acc[im][in][q] + bv));
                }
        } else if (blk < 52 && t > 0) {
            int u = blk - 36;
            fc_tile(p, (u >> 2) * 64, (u & 3) * 64, t - 1,
                    sm.g.As, sm.g.Bs, sm.g.ypart, tid);
        }
        gbar(p.bar, blk < 36);

        // ---- phase B: attn2 -> fp32 logits (36 tiles) ----
        if (blk < 36) {
            int m0 = (blk / 9) * 64, n0 = (blk % 9) * 64;
            f4 acc[2][2] = {};
            gemm64(p.s1 + m0 * T_, T_, p.W2b + n0 * T_, T_, T_,
                   sm.g.As, sm.g.Bs, tid, acc);
            int colb = n0 + wn + (lane & 15);
            int rowb = m0 + wm + (lane >> 4) * 4;
            #pragma unroll
            for (int im = 0; im < 2; im++)
                #pragma unroll
                for (int in = 0; in < 2; in++) {
                    int col = colb + in * 16;
                    float bv = p.ab2[col];
                    #pragma unroll
                    for (int q = 0; q < 4; q++)
                        p.logit[(rowb + im * 16 + q) * T_ + col] = acc[im][in][q] + bv;
                }
        }
        gbar(p.bar, blk < 36);

        // ---- phase C: softmax*alpha + weighted enc sum (1 block per batch) ----
        {
            int b = blk;
            const float* lg = p.logit + b * T_;
            float l0 = lg[tid], l1 = lg[tid + 256];
            float l2 = (tid < 64) ? lg[tid + 512] : -INFINITY;
            float mx = fmaxf(fmaxf(l0, l1), l2);
            for (int off = 32; off; off >>= 1) mx = fmaxf(mx, __shfl_xor(mx, off));
            if (lane == 0) sm.c.red4[w] = mx;
            __syncthreads();
            mx = fmaxf(fmaxf(sm.c.red4[0], sm.c.red4[1]),
                       fmaxf(sm.c.red4[2], sm.c.red4[3]));
            float e0 = expf(l0 - mx), e1 = expf(l1 - mx);
            float e2 = (tid < 64) ? expf(l2 - mx) : 0.f;
            float sme = e0 + e1 + e2;
            for (int off = 32; off; off >>= 1) sme += __shfl_xor(sme, off);
            __syncthreads();
            if (lane == 0) sm.c.red4[w] = sme;
            __syncthreads();
            float inv = 1.f / (sm.c.red4[0] + sm.c.red4[1] + sm.c.red4[2] + sm.c.red4[3]);
            const float* al = p.alpha + b * 24;
            sm.c.wt[tid]       = e0 * inv * al[tid / 24];
            sm.c.wt[tid + 256] = e1 * inv * al[(tid + 256) / 24];
            if (tid < 64) sm.c.wt[tid + 512] = e2 * inv * al[(tid + 512) / 24];
            __syncthreads();
            // accumulate: oct = 8 channels per thread, rp = row phase (4)
            int oct = tid & 63, rp = tid >> 6;
            const short* ebase = p.encb + (size_t)b * T_ * E_ + oct * 8;
            float a0 = 0.f, a1 = 0.f, a2 = 0.f, a3 = 0.f;
            float a4 = 0.f, a5 = 0.f, a6 = 0.f, a7 = 0.f;
            #pragma unroll 8
            for (int r = rp; r < T_; r += 4) {
                float wv = sm.c.wt[r];
                int4 v = *(const int4*)(ebase + (size_t)r * E_);
                a0 += wv * bf2f((unsigned short)v.x);
                a1 += wv * bf2f((unsigned short)(((unsigned)v.x) >> 16));
                a2 += wv * bf2f((unsigned short)v.y);
                a3 += wv * bf2f((unsigned short)(((unsigned)v.y) >> 16));
                a4 += wv * bf2f((unsigned short)v.z);
                a5 += wv * bf2f((unsigned short)(((unsigned)v.z) >> 16));
                a6 += wv * bf2f((unsigned short)v.w);
                a7 += wv * bf2f((unsigned short)(((unsigned)v.w) >> 16));
            }
            float* rr = &sm.c.red[rp][oct * 8];
            rr[0] = a0; rr[1] = a1; rr[2] = a2; rr[3] = a3;
            rr[4] = a4; rr[5] = a5; rr[6] = a6; rr[7] = a7;
            __syncthreads();
            float s0 = 0.f, s1v = 0.f;
            #pragma unroll
            for (int q = 0; q < 4; q++) {
                s0  += sm.c.red[q][tid * 2];
                s1v += sm.c.red[q][tid * 2 + 1];
            }
            p.ctxp[b * E_ + tid * 2]     = s0;
            p.ctxp[b * E_ + tid * 2 + 1] = s1v;
        }
        gbar(p.bar, true);

        // ---- phase D: gates GEMM + fused LSTM pointwise (128 tiles) ----
        if (blk < 128) {
            int n0 = (blk & 31) * 64, m0 = (blk >> 5) * 64;
            int fr = lane & 15, fk = (lane >> 4) * 8;
            int r = tid >> 2, c0 = (tid & 3) * 16, c8 = (tid & 3) * 8;
            f4 acc[2][2] = {};
            // phase 1: inp = [ctx | ff_t], K = 544
            for (int k0 = 0; k0 < KX_; k0 += 64) {
                int rem = KX_ - k0;
                if (rem >= 64) {
                    const float* cp = p.ctxp + (m0 + r) * E_ + k0 + c0;
                    short av[16];
                    #pragma unroll
                    for (int i = 0; i < 16; i++) av[i] = f2bf(cp[i]);
                    *(int4*)&sm.g.As[r][c0]     = *(int4*)&av[0];
                    *(int4*)&sm.g.As[r][c0 + 8] = *(int4*)&av[8];
                    *(int4*)&sm.g.Bs[r][c0]     = *(const int4*)(p.Wihb + (n0 + r) * KX_ + k0 + c0);
                    *(int4*)&sm.g.Bs[r][c0 + 8] = *(const int4*)(p.Wihb + (n0 + r) * KX_ + k0 + c0 + 8);
                } else {
                    const float* fp = p.ff + ((m0 + r) * FT_ + t) * M_ + (k0 + c8 - E_);
                    short av[8];
                    #pragma unroll
                    for (int i = 0; i < 8; i++) av[i] = f2bf(fp[i]);
                    *(int4*)&sm.g.As[r][c8] = *(int4*)&av[0];
                    *(int4*)&sm.g.Bs[r][c8] = *(const int4*)(p.Wihb + (n0 + r) * KX_ + k0 + c8);
                }
                __syncthreads();
                mfma4(sm.g.As, sm.g.Bs, wm, wn, fr, fk, acc);
                if (rem >= 64) mfma4(sm.g.As, sm.g.Bs, wm, wn, fr, fk + 32, acc);
                __syncthreads();
            }
            // phase 2: + h_{t-1}[d] * Whh^T, K = 256
            int d = n0 >> 10;
            const short* hprev = (t & 1) ? p.hB : p.hA;
            short* hnext       = (t & 1) ? p.hA : p.hB;
            gemm64(hprev + d * B_ * H_ + m0 * H_, H_, p.Whhb + n0 * H_, H_, H_,
                   sm.g.As, sm.g.Bs, tid, acc);
            // epilogue: +bias -> LDS, then LSTM pointwise
            int clb = wn + (lane & 15);
            int rlb = wm + (lane >> 4) * 4;
            #pragma unroll
            for (int im = 0; im < 2; im++)
                #pragma unroll
                for (int in = 0; in < 2; in++) {
                    int cl = clb + in * 16;
                    float bv = p.bcomb[n0 + cl];
                    #pragma unroll
                    for (int q = 0; q < 4; q++)
                        sm.gt[rlb + im * 16 + q][cl] = acc[im][in][q] + bv;
                }
            __syncthreads();
            int j0 = (n0 >> 2) & 255;
            #pragma unroll
            for (int it = 0; it < 4; it++) {
                int item = tid + it * 256;
                int rl = item >> 4, ql = item & 15;
                float ig = sm.gt[rl][ql * 4 + 0];
                float fg = sm.gt[rl][ql * 4 + 1];
                float gg = sm.gt[rl][ql * 4 + 2];
                float og = sm.gt[rl][ql * 4 + 3];
                int b = m0 + rl, j = j0 + ql;
                int ci = d * 65536 + b * 256 + j;
                float cn = sigm(fg) * p.cbuf[ci] + sigm(ig) * tanhf(gg);
                float hn = sigm(og) * tanhf(cn);
                p.cbuf[ci] = cn;
                short hv = f2bf(hn);
                p.xb[b * KX_ + d * H_ + j] = hv;
                hnext[ci] = hv;
                if (d == 0 && j < M_ && t + 1 < FT_)
                    p.xb[b * KX_ + E_ + j] = f2bf(p.ff[(b * FT_ + t + 1) * M_ + j]);
                if (n0 == 0 && ql == 0) p.out[b * FT_ + t] = p.fb2[0];
            }
        }
        gbar(p.bar, blk < 128);
    }
    // tail fc for the last step
    if (blk < 16)
        fc_tile(p, (blk >> 2) * 64, (blk & 3) * 64, FT_ - 1,
                sm.g.As, sm.g.Bs, sm.g.ypart, tid);
}

extern "C" void kernel_launch(void* const* d_in, const int* in_sizes, int n_in,
                              void* d_out, int out_size, void* d_ws, size_t ws_size,
                              hipStream_t stream) {
    (void)in_sizes; (void)n_in; (void)out_size; (void)ws_size;
    const float* enc_f  = (const float*)d_in[0];
    const float* fhist  = (const float*)d_in[1];
    const float* ff     = (const float*)d_in[3];
    const float* hidden = (const float*)d_in[4];
    const float* cell   = (const float*)d_in[5];
    const float* aW1    = (const float*)d_in[6];
    const float* ab1    = (const float*)d_in[7];
    const float* aW2    = (const float*)d_in[8];
    const float* ab2    = (const float*)d_in[9];
    const float* Wih    = (const float*)d_in[10];
    const float* Whh    = (const float*)d_in[11];
    const float* bih    = (const float*)d_in[12];
    const float* bhh    = (const float*)d_in[13];
    const float* fW1    = (const float*)d_in[14];
    const float* fb1    = (const float*)d_in[15];
    const float* fW2    = (const float*)d_in[16];
    const float* fb2    = (const float*)d_in[17];
    float* out = (float*)d_out;

    char* pws = (char*)d_ws;
    auto take = [&](size_t n) { char* r = pws; pws += (n + 255) & ~(size_t)255; return r; };
    unsigned* bar = (unsigned*)take(256);
    float* alpha = (float*)take(B_ * 24 * 4);
    short* xb    = (short*)take(B_ * KX_ * 2);
    short* hA    = (short*)take(2 * B_ * H_ * 2);
    short* hB    = (short*)take(2 * B_ * H_ * 2);
    float* cbuf  = (float*)take(2 * B_ * H_ * 4);
    short* s1    = (short*)take(B_ * T_ * 2);
    float* logit = (float*)take(B_ * T_ * 4);
    float* ctxp  = (float*)take(B_ * E_ * 4);
    float* bcomb = (float*)take(ND_ * 4);
    short* W1b   = (short*)take(T_ * KX_ * 2);
    short* W2b   = (short*)take(T_ * T_ * 2);
    short* Wihb  = (short*)take(ND_ * KX_ * 2);
    short* Whhb  = (short*)take(ND_ * H_ * 2);
    short* fW1b  = (short*)take(H_ * E_ * 2);
    short* encb  = (short*)take((size_t)B_ * T_ * E_ * 2);

    SetupPrm sp;
    sp.enc = enc_f; sp.fhist = fhist; sp.ff = ff; sp.hidden = hidden; sp.cell = cell;
    sp.aW1 = aW1; sp.aW2 = aW2; sp.Wih = Wih; sp.Whh = Whh; sp.bih = bih; sp.bhh = bhh;
    sp.fW1 = fW1;
    sp.W1b = W1b; sp.W2b = W2b; sp.Wihb = Wihb; sp.Whhb = Whhb; sp.fW1b = fW1b;
    sp.encb = encb; sp.xb = xb; sp.hA = hA;
    sp.bcomb = bcomb; sp.alpha = alpha; sp.cbuf = cbuf;
    sp.bar = bar;

    k_setup<<<2048, 256, 0, stream>>>(sp);

    LoopPrm lp;
    lp.xb = xb;
    lp.W1b = W1b; lp.W2b = W2b; lp.Wihb = Wihb; lp.Whhb = Whhb; lp.fW1b = fW1b;
    lp.encb = encb;
    lp.ab1 = ab1; lp.ab2 = ab2; lp.fb1 = fb1; lp.fW2 = fW2; lp.fb2 = fb2; lp.ff = ff;
    lp.bcomb = bcomb; lp.alpha = alpha;
    lp.s1 = s1; lp.logit = logit; lp.ctxp = ctxp; lp.cbuf = cbuf;
    lp.hA = hA; lp.hB = hB;
    lp.out = out;
    lp.bar = bar;

    k_loop<<<NBLK, 256, 0, stream>>>(lp);
}

// Round 5
// 2938.490 us; speedup vs baseline: 2.0952x; 1.4114x over previous
//
#include <hip/hip_runtime.h>
#include <math.h>

#define B_ 256
#define T_ 576
#define FT_ 24
#define M_ 32
#define H_ 256
#define E_ 512
#define KX_ 544   // E + M
#define ND_ 2048  // 2*4H
#define EPS_ 1e-6f
#define LDAS 72   // 64 + 8 pad (shorts)
#define NBLK 256

typedef __attribute__((ext_vector_type(8))) short bf8;   // 8 bf16 (4 VGPRs)
typedef __attribute__((ext_vector_type(4))) float f4;

__device__ __forceinline__ float bf2f(unsigned short s) {
    union { unsigned u; float f; } c; c.u = ((unsigned)s) << 16; return c.f;
}
__device__ __forceinline__ short f2bf(float f) {
    union { float f; unsigned u; } c; c.f = f;
    unsigned r = c.u + 0x7fffu + ((c.u >> 16) & 1u);
    return (short)(r >> 16);
}
__device__ __forceinline__ float sigm(float x) { return 1.f / (1.f + expf(-x)); }

// ---- coherence-point (L1/L2-bypass, device-scope) accessors for CROSSING buffers.
// Relaxed atomics emit sc-flagged loads/stores the compiler schedules normally
// (pipelining preserved, no fences, no cache invalidates).
__device__ __forceinline__ unsigned long long ldg_u64(const void* p) {
    return __hip_atomic_load((unsigned long long*)p, __ATOMIC_RELAXED,
                             __HIP_MEMORY_SCOPE_AGENT);
}
__device__ __forceinline__ int4 ldg_b128(const void* p) {
    union { int4 v; unsigned long long q[2]; } u;
    u.q[0] = ldg_u64(p);
    u.q[1] = ldg_u64((const char*)p + 8);
    return u.v;
}
__device__ __forceinline__ float ldg_f32(const float* p) {
    union { float f; unsigned u; } c;
    c.u = __hip_atomic_load((unsigned*)p, __ATOMIC_RELAXED, __HIP_MEMORY_SCOPE_AGENT);
    return c.f;
}
__device__ __forceinline__ void stg_u16(short* p, short v) {
    __hip_atomic_store(p, v, __ATOMIC_RELAXED, __HIP_MEMORY_SCOPE_AGENT);
}
__device__ __forceinline__ void stg_f32(float* p, float v) {
    union { float f; unsigned u; } c; c.f = v;
    __hip_atomic_store((unsigned*)p, c.u, __ATOMIC_RELAXED, __HIP_MEMORY_SCOPE_AGENT);
}

// MONOTONIC grid barrier: counter only ever increases; barrier k waits for
// bar[0] >= k*NBLK. No reset -> no reset/arrive race (round-4 deadlock),
// no release/acquire fences (round-3 L2-writeback/invalidate storms).
// Data visibility: vmcnt(0) drain + __syncthreads BEFORE the arrive-add
// guarantees this block's coherence-point stores are globally visible.
__device__ __forceinline__ void gbar(unsigned* bar, unsigned target) {
    asm volatile("s_waitcnt vmcnt(0)" ::: "memory");
    __syncthreads();
    if (threadIdx.x == 0) {
        __hip_atomic_fetch_add(&bar[0], 1u, __ATOMIC_RELAXED, __HIP_MEMORY_SCOPE_AGENT);
        while (__hip_atomic_load(&bar[0], __ATOMIC_RELAXED, __HIP_MEMORY_SCOPE_AGENT) < target)
            __builtin_amdgcn_s_sleep(8);
    }
    __syncthreads();
}

__device__ __forceinline__ void mfma4(const short (*As)[LDAS], const short (*Bs)[LDAS],
                                      int wm, int wn, int fr, int fk, f4 acc[2][2]) {
    bf8 a0 = *(const bf8*)&As[wm + fr][fk];
    bf8 a1 = *(const bf8*)&As[wm + 16 + fr][fk];
    bf8 b0 = *(const bf8*)&Bs[wn + fr][fk];
    bf8 b1 = *(const bf8*)&Bs[wn + 16 + fr][fk];
    acc[0][0] = __builtin_amdgcn_mfma_f32_16x16x32_bf16(a0, b0, acc[0][0], 0, 0, 0);
    acc[0][1] = __builtin_amdgcn_mfma_f32_16x16x32_bf16(a0, b1, acc[0][1], 0, 0, 0);
    acc[1][0] = __builtin_amdgcn_mfma_f32_16x16x32_bf16(a1, b0, acc[1][0], 0, 0, 0);
    acc[1][1] = __builtin_amdgcn_mfma_f32_16x16x32_bf16(a1, b1, acc[1][1], 0, 0, 0);
}

// 64x64 output tile GEMM, BK=64 (tail 32 ok): acc += A[64xK] * Wt[64xK]^T
// A-operand is a CROSSING buffer -> coherence-point loads; Wt is a read-only
// weight -> plain loads (stays L2-resident across steps).
__device__ __forceinline__ void gemm64(const short* __restrict__ A, int lda,
                                       const short* __restrict__ Wt, int ldw, int K,
                                       short (*As)[LDAS], short (*Bs)[LDAS], int tid,
                                       f4 acc[2][2]) {
    int lane = tid & 63, w = tid >> 6;
    int wm = (w & 1) * 32, wn = (w >> 1) * 32;
    int fr = lane & 15, fk = (lane >> 4) * 8;
    int r = tid >> 2, c0 = (tid & 3) * 16, c8 = (tid & 3) * 8;
    int4 pa0, pa1, pb0, pb1;
    auto ld = [&](int k0) {
        if (K - k0 >= 64) {
            pa0 = ldg_b128(A + r * lda + k0 + c0);
            pa1 = ldg_b128(A + r * lda + k0 + c0 + 8);
            pb0 = *(const int4*)(Wt + r * ldw + k0 + c0);
            pb1 = *(const int4*)(Wt + r * ldw + k0 + c0 + 8);
        } else {
            pa0 = ldg_b128(A + r * lda + k0 + c8);
            pb0 = *(const int4*)(Wt + r * ldw + k0 + c8);
        }
    };
    ld(0);
    for (int k0 = 0; k0 < K; k0 += 64) {
        int rem = K - k0;
        if (rem >= 64) {
            *(int4*)&As[r][c0] = pa0; *(int4*)&As[r][c0 + 8] = pa1;
            *(int4*)&Bs[r][c0] = pb0; *(int4*)&Bs[r][c0 + 8] = pb1;
        } else {
            *(int4*)&As[r][c8] = pa0;
            *(int4*)&Bs[r][c8] = pb0;
        }
        __syncthreads();
        if (k0 + 64 < K) ld(k0 + 64);
        mfma4(As, Bs, wm, wn, fr, fk, acc);
        if (rem >= 64) mfma4(As, Bs, wm, wn, fr, fk + 32, acc);
        __syncthreads();
    }
}

// ---------------- fused setup: casts, gate-permuted weights, bias, alpha, init ----------------
struct SetupPrm {
    const float *enc, *fhist, *ff, *hidden, *cell;
    const float *aW1, *aW2, *Wih, *Whh, *bih, *bhh, *fW1;
    short *W1b, *W2b, *Wihb, *Whhb, *fW1b, *encb, *xb, *hA;
    float *bcomb, *alpha, *cbuf;
    unsigned *bar;
};

__global__ __launch_bounds__(256) void k_setup(SetupPrm p) {
    const int NT = 2048 * 256;
    int gt = blockIdx.x * 256 + threadIdx.x;
    if (gt == 0) { p.bar[0] = 0; p.bar[1] = 0; }
    auto cast = [&](const float* s, short* d, int n4) {
        for (int i = gt; i < n4; i += NT) {
            float4 v = ((const float4*)s)[i];
            short4 o; o.x = f2bf(v.x); o.y = f2bf(v.y); o.z = f2bf(v.z); o.w = f2bf(v.w);
            ((short4*)d)[i] = o;
        }
    };
    cast(p.aW1, p.W1b, T_ * KX_ / 4);
    cast(p.aW2, p.W2b, T_ * T_ / 4);
    cast(p.fW1, p.fW1b, H_ * E_ / 4);
    cast(p.enc, p.encb, B_ * T_ * E_ / 4);
    // gate-permuted Wih: new row d*1024 + j*4 + g  <-  orig d*1024 + g*256 + j
    for (int i = gt; i < ND_ * KX_ / 4; i += NT) {
        int row = i / (KX_ / 4), c4 = i % (KX_ / 4);
        int d = row >> 10, rest = row & 1023, j = rest >> 2, g = rest & 3;
        int orig = d * 1024 + g * 256 + j;
        float4 v = ((const float4*)(p.Wih + orig * KX_))[c4];
        short4 o; o.x = f2bf(v.x); o.y = f2bf(v.y); o.z = f2bf(v.z); o.w = f2bf(v.w);
        ((short4*)(p.Wihb + row * KX_))[c4] = o;
    }
    for (int i = gt; i < ND_ * H_ / 4; i += NT) {
        int row = i / (H_ / 4), c4 = i % (H_ / 4);
        int d = row >> 10, rest = row & 1023, j = rest >> 2, g = rest & 3;
        int orig = d * 1024 + g * 256 + j;
        float4 v = ((const float4*)(p.Whh + orig * H_))[c4];
        short4 o; o.x = f2bf(v.x); o.y = f2bf(v.y); o.z = f2bf(v.z); o.w = f2bf(v.w);
        ((short4*)(p.Whhb + row * H_))[c4] = o;
    }
    for (int i = gt; i < ND_; i += NT) {
        int d = i >> 10, rest = i & 1023, j = rest >> 2, g = rest & 3;
        int orig = d * 1024 + g * 256 + j;
        p.bcomb[i] = p.bih[orig] + p.bhh[orig];
    }
    // init: x0 = [h0|h1|ff0] bf16, hA = h0 bf16, c fp32
    for (int i = gt; i < 2 * B_ * H_; i += NT) {
        int d = i >> 16, b = (i >> 8) & 255, j = i & 255;
        short hv = f2bf(p.hidden[i]);
        p.xb[b * KX_ + d * H_ + j] = hv;
        p.hA[i] = hv;                       // layout [d][b][j] == flat i
        p.cbuf[i] = p.cell[i];
        if (d == 0 && j < M_) p.xb[b * KX_ + E_ + j] = f2bf(p.ff[b * FT_ * M_ + j]);
    }
    // alpha softmax (one wave per batch, blocks 0..255)
    if (blockIdx.x < 256 && threadIdx.x < 64) {
        int b = blockIdx.x, t = threadIdx.x;
        float dp = 0.f;
        if (t < 24) {
            float fv[M_];
            const float* fp = p.ff + (b * FT_ + t) * M_;
            #pragma unroll
            for (int m = 0; m < M_; m++) fv[m] = fp[m];
            float dist = 0.f;
            for (int pp = 0; pp < 24; pp++) {
                const float* hp = p.fhist + (b * T_ + pp * 24 + t) * M_;
                float s = 0.f;
                #pragma unroll
                for (int m = 0; m < M_; m++) { float d = fv[m] - hp[m] + EPS_; s += d * d; }
                dist += sqrtf(s);
            }
            dp = 1.f / dist;
        }
        float v = (t < 24) ? dp : -INFINITY;
        float mx = v;
        for (int off = 32; off; off >>= 1) mx = fmaxf(mx, __shfl_xor(mx, off));
        float e = (t < 24) ? expf(dp - mx) : 0.f;
        float sme = e;
        for (int off = 32; off; off >>= 1) sme += __shfl_xor(sme, off);
        if (t < 24) p.alpha[b * 24 + t] = e / sme;
    }
}

// ---------------- persistent loop kernel (plain launch + monotonic grid barrier) ----------------
struct LoopPrm {
    short *xb;
    const short *W1b, *W2b, *Wihb, *Whhb, *fW1b, *encb;
    const float *ab1, *ab2, *fb1, *fW2, *fb2, *ff;
    const float *bcomb, *alpha;
    short *s1;
    float *logit, *ctxp, *cbuf;
    short *hA, *hB;
    float *out;
    unsigned *bar;
};

__device__ __forceinline__ void fc_tile(const LoopPrm& p, int m0, int n0, int step,
                                        short (*As)[LDAS], short (*Bs)[LDAS],
                                        float* ypart, int tid) {
    f4 acc[2][2] = {};
    gemm64(p.xb + m0 * KX_, KX_, p.fW1b + n0 * E_, E_, E_, As, Bs, tid, acc);
    if (tid < 64) ypart[tid] = 0.f;
    __syncthreads();
    int lane = tid & 63, w = tid >> 6;
    int wm = (w & 1) * 32, wn = (w >> 1) * 32;
    int colb = n0 + wn + (lane & 15);
    int rloc = wm + (lane >> 4) * 4;
    #pragma unroll
    for (int im = 0; im < 2; im++)
        #pragma unroll
        for (int q = 0; q < 4; q++) {
            float s = 0.f;
            #pragma unroll
            for (int in = 0; in < 2; in++) {
                int col = colb + in * 16;
                s += fmaxf(acc[im][in][q] + p.fb1[col], 0.f) * p.fW2[col];
            }
            #pragma unroll
            for (int off = 1; off < 16; off <<= 1) s += __shfl_xor(s, off);
            if ((lane & 15) == 0) atomicAdd(&ypart[rloc + im * 16 + q], s);
        }
    __syncthreads();
    if (tid < 64) atomicAdd(&p.out[(m0 + tid) * FT_ + step], ypart[tid]);
}

__global__ __launch_bounds__(256) void k_loop(LoopPrm p) {
    __shared__ union {
        struct { short As[64][LDAS]; short Bs[64][LDAS]; float ypart[64]; } g;
        struct { float wt[T_]; float red4[4]; float red[4][512]; } c;
        float gt[64][68];
    } sm;
    const int blk = blockIdx.x, tid = threadIdx.x;
    const int lane = tid & 63, w = tid >> 6;
    const int wm = (w & 1) * 32, wn = (w >> 1) * 32;
    unsigned tgt = 0;   // monotonic barrier target

    for (int t = 0; t < FT_; t++) {
        // ---- phase A: attn1 (36 tiles) + fc of previous step (16 tiles) ----
        if (blk < 36) {
            int m0 = (blk / 9) * 64, n0 = (blk % 9) * 64;
            f4 acc[2][2] = {};
            gemm64(p.xb + m0 * KX_, KX_, p.W1b + n0 * KX_, KX_, KX_,
                   sm.g.As, sm.g.Bs, tid, acc);
            int colb = n0 + wn + (lane & 15);
            int rowb = m0 + wm + (lane >> 4) * 4;
            #pragma unroll
            for (int im = 0; im < 2; im++)
                #pragma unroll
                for (int in = 0; in < 2; in++) {
                    int col = colb + in * 16;
                    float bv = p.ab1[col];
                    #pragma unroll
                    for (int q = 0; q < 4; q++)
                        stg_u16(&p.s1[(rowb + im * 16 + q) * T_ + col],
                                f2bf(tanhf(acc[im][in][q] + bv)));
                }
        } else if (blk < 52 && t > 0) {
            int u = blk - 36;
            fc_tile(p, (u >> 2) * 64, (u & 3) * 64, t - 1,
                    sm.g.As, sm.g.Bs, sm.g.ypart, tid);
        }
        tgt += NBLK; gbar(p.bar, tgt);

        // ---- phase B: attn2 -> fp32 logits (36 tiles) ----
        if (blk < 36) {
            int m0 = (blk / 9) * 64, n0 = (blk % 9) * 64;
            f4 acc[2][2] = {};
            gemm64(p.s1 + m0 * T_, T_, p.W2b + n0 * T_, T_, T_,
                   sm.g.As, sm.g.Bs, tid, acc);
            int colb = n0 + wn + (lane & 15);
            int rowb = m0 + wm + (lane >> 4) * 4;
            #pragma unroll
            for (int im = 0; im < 2; im++)
                #pragma unroll
                for (int in = 0; in < 2; in++) {
                    int col = colb + in * 16;
                    float bv = p.ab2[col];
                    #pragma unroll
                    for (int q = 0; q < 4; q++)
                        stg_f32(&p.logit[(rowb + im * 16 + q) * T_ + col],
                                acc[im][in][q] + bv);
                }
        }
        tgt += NBLK; gbar(p.bar, tgt);

        // ---- phase C: softmax*alpha + weighted enc sum (1 block per batch) ----
        {
            int b = blk;
            const float* lg = p.logit + b * T_;
            float l0 = ldg_f32(lg + tid), l1 = ldg_f32(lg + tid + 256);
            float l2 = (tid < 64) ? ldg_f32(lg + tid + 512) : -INFINITY;
            float mx = fmaxf(fmaxf(l0, l1), l2);
            for (int off = 32; off; off >>= 1) mx = fmaxf(mx, __shfl_xor(mx, off));
            if (lane == 0) sm.c.red4[w] = mx;
            __syncthreads();
            mx = fmaxf(fmaxf(sm.c.red4[0], sm.c.red4[1]),
                       fmaxf(sm.c.red4[2], sm.c.red4[3]));
            float e0 = expf(l0 - mx), e1 = expf(l1 - mx);
            float e2 = (tid < 64) ? expf(l2 - mx) : 0.f;
            float sme = e0 + e1 + e2;
            for (int off = 32; off; off >>= 1) sme += __shfl_xor(sme, off);
            __syncthreads();
            if (lane == 0) sm.c.red4[w] = sme;
            __syncthreads();
            float inv = 1.f / (sm.c.red4[0] + sm.c.red4[1] + sm.c.red4[2] + sm.c.red4[3]);
            const float* al = p.alpha + b * 24;
            sm.c.wt[tid]       = e0 * inv * al[tid / 24];
            sm.c.wt[tid + 256] = e1 * inv * al[(tid + 256) / 24];
            if (tid < 64) sm.c.wt[tid + 512] = e2 * inv * al[(tid + 512) / 24];
            __syncthreads();
            // accumulate: oct = 8 channels per thread, rp = row phase (4)
            int oct = tid & 63, rp = tid >> 6;
            const short* ebase = p.encb + (size_t)b * T_ * E_ + oct * 8;
            float a0 = 0.f, a1 = 0.f, a2 = 0.f, a3 = 0.f;
            float a4 = 0.f, a5 = 0.f, a6 = 0.f, a7 = 0.f;
            #pragma unroll 8
            for (int r = rp; r < T_; r += 4) {
                float wv = sm.c.wt[r];
                int4 v = *(const int4*)(ebase + (size_t)r * E_);
                a0 += wv * bf2f((unsigned short)v.x);
                a1 += wv * bf2f((unsigned short)(((unsigned)v.x) >> 16));
                a2 += wv * bf2f((unsigned short)v.y);
                a3 += wv * bf2f((unsigned short)(((unsigned)v.y) >> 16));
                a4 += wv * bf2f((unsigned short)v.z);
                a5 += wv * bf2f((unsigned short)(((unsigned)v.z) >> 16));
                a6 += wv * bf2f((unsigned short)v.w);
                a7 += wv * bf2f((unsigned short)(((unsigned)v.w) >> 16));
            }
            float* rr = &sm.c.red[rp][oct * 8];
            rr[0] = a0; rr[1] = a1; rr[2] = a2; rr[3] = a3;
            rr[4] = a4; rr[5] = a5; rr[6] = a6; rr[7] = a7;
            __syncthreads();
            float s0 = 0.f, s1v = 0.f;
            #pragma unroll
            for (int q = 0; q < 4; q++) {
                s0  += sm.c.red[q][tid * 2];
                s1v += sm.c.red[q][tid * 2 + 1];
            }
            stg_f32(&p.ctxp[b * E_ + tid * 2], s0);
            stg_f32(&p.ctxp[b * E_ + tid * 2 + 1], s1v);
        }
        tgt += NBLK; gbar(p.bar, tgt);

        // ---- phase D: gates GEMM + fused LSTM pointwise (128 tiles) ----
        if (blk < 128) {
            int n0 = (blk & 31) * 64, m0 = (blk >> 5) * 64;
            int fr = lane & 15, fk = (lane >> 4) * 8;
            int r = tid >> 2, c0 = (tid & 3) * 16, c8 = (tid & 3) * 8;
            f4 acc[2][2] = {};
            // phase 1: inp = [ctx | ff_t], K = 544
            for (int k0 = 0; k0 < KX_; k0 += 64) {
                int rem = KX_ - k0;
                if (rem >= 64) {
                    const float* cp = p.ctxp + (m0 + r) * E_ + k0 + c0;
                    short av[16];
                    #pragma unroll
                    for (int i = 0; i < 8; i++) {
                        union { unsigned long long q; float f[2]; } u;
                        u.q = ldg_u64(cp + i * 2);
                        av[2 * i]     = f2bf(u.f[0]);
                        av[2 * i + 1] = f2bf(u.f[1]);
                    }
                    *(int4*)&sm.g.As[r][c0]     = *(int4*)&av[0];
                    *(int4*)&sm.g.As[r][c0 + 8] = *(int4*)&av[8];
                    *(int4*)&sm.g.Bs[r][c0]     = *(const int4*)(p.Wihb + (n0 + r) * KX_ + k0 + c0);
                    *(int4*)&sm.g.Bs[r][c0 + 8] = *(const int4*)(p.Wihb + (n0 + r) * KX_ + k0 + c0 + 8);
                } else {
                    const float* fp = p.ff + ((m0 + r) * FT_ + t) * M_ + (k0 + c8 - E_);
                    short av[8];
                    #pragma unroll
                    for (int i = 0; i < 8; i++) av[i] = f2bf(fp[i]);
                    *(int4*)&sm.g.As[r][c8] = *(int4*)&av[0];
                    *(int4*)&sm.g.Bs[r][c8] = *(const int4*)(p.Wihb + (n0 + r) * KX_ + k0 + c8);
                }
                __syncthreads();
                mfma4(sm.g.As, sm.g.Bs, wm, wn, fr, fk, acc);
                if (rem >= 64) mfma4(sm.g.As, sm.g.Bs, wm, wn, fr, fk + 32, acc);
                __syncthreads();
            }
            // phase 2: + h_{t-1}[d] * Whh^T, K = 256
            int d = n0 >> 10;
            const short* hprev = (t & 1) ? p.hB : p.hA;
            short* hnext       = (t & 1) ? p.hA : p.hB;
            gemm64(hprev + d * B_ * H_ + m0 * H_, H_, p.Whhb + n0 * H_, H_,
                   H_, sm.g.As, sm.g.Bs, tid, acc);
            // epilogue: +bias -> LDS, then LSTM pointwise
            int clb = wn + (lane & 15);
            int rlb = wm + (lane >> 4) * 4;
            #pragma unroll
            for (int im = 0; im < 2; im++)
                #pragma unroll
                for (int in = 0; in < 2; in++) {
                    int cl = clb + in * 16;
                    float bv = p.bcomb[n0 + cl];
                    #pragma unroll
                    for (int q = 0; q < 4; q++)
                        sm.gt[rlb + im * 16 + q][cl] = acc[im][in][q] + bv;
                }
            __syncthreads();
            int j0 = (n0 >> 2) & 255;
            #pragma unroll
            for (int it = 0; it < 4; it++) {
                int item = tid + it * 256;
                int rl = item >> 4, ql = item & 15;
                float ig = sm.gt[rl][ql * 4 + 0];
                float fg = sm.gt[rl][ql * 4 + 1];
                float gg = sm.gt[rl][ql * 4 + 2];
                float og = sm.gt[rl][ql * 4 + 3];
                int b = m0 + rl, j = j0 + ql;
                int ci = d * 65536 + b * 256 + j;
                float cn = sigm(fg) * p.cbuf[ci] + sigm(ig) * tanhf(gg);
                float hn = sigm(og) * tanhf(cn);
                p.cbuf[ci] = cn;                      // block-private: plain is safe
                short hv = f2bf(hn);
                stg_u16(&p.xb[b * KX_ + d * H_ + j], hv);
                stg_u16(&hnext[ci], hv);
                if (d == 0 && j < M_ && t + 1 < FT_)
                    stg_u16(&p.xb[b * KX_ + E_ + j], f2bf(p.ff[(b * FT_ + t + 1) * M_ + j]));
                if (n0 == 0 && ql == 0) stg_f32(&p.out[b * FT_ + t], p.fb2[0]);
            }
        }
        tgt += NBLK; gbar(p.bar, tgt);
    }
    // tail fc for the last step
    if (blk < 16)
        fc_tile(p, (blk >> 2) * 64, (blk & 3) * 64, FT_ - 1,
                sm.g.As, sm.g.Bs, sm.g.ypart, tid);
}

extern "C" void kernel_launch(void* const* d_in, const int* in_sizes, int n_in,
                              void* d_out, int out_size, void* d_ws, size_t ws_size,
                              hipStream_t stream) {
    (void)in_sizes; (void)n_in; (void)out_size; (void)ws_size;
    const float* enc_f  = (const float*)d_in[0];
    const float* fhist  = (const float*)d_in[1];
    const float* ff     = (const float*)d_in[3];
    const float* hidden = (const float*)d_in[4];
    const float* cell   = (const float*)d_in[5];
    const float* aW1    = (const float*)d_in[6];
    const float* ab1    = (const float*)d_in[7];
    const float* aW2    = (const float*)d_in[8];
    const float* ab2    = (const float*)d_in[9];
    const float* Wih    = (const float*)d_in[10];
    const float* Whh    = (const float*)d_in[11];
    const float* bih    = (const float*)d_in[12];
    const float* bhh    = (const float*)d_in[13];
    const float* fW1    = (const float*)d_in[14];
    const float* fb1    = (const float*)d_in[15];
    const float* fW2    = (const float*)d_in[16];
    const float* fb2    = (const float*)d_in[17];
    float* out = (float*)d_out;

    char* pws = (char*)d_ws;
    auto take = [&](size_t n) { char* r = pws; pws += (n + 255) & ~(size_t)255; return r; };
    unsigned* bar = (unsigned*)take(256);
    float* alpha = (float*)take(B_ * 24 * 4);
    short* xb    = (short*)take(B_ * KX_ * 2);
    short* hA    = (short*)take(2 * B_ * H_ * 2);
    short* hB    = (short*)take(2 * B_ * H_ * 2);
    float* cbuf  = (float*)take(2 * B_ * H_ * 4);
    short* s1    = (short*)take(B_ * T_ * 2);
    float* logit = (float*)take(B_ * T_ * 4);
    float* ctxp  = (float*)take(B_ * E_ * 4);
    float* bcomb = (float*)take(ND_ * 4);
    short* W1b   = (short*)take(T_ * KX_ * 2);
    short* W2b   = (short*)take(T_ * T_ * 2);
    short* Wihb  = (short*)take(ND_ * KX_ * 2);
    short* Whhb  = (short*)take(ND_ * H_ * 2);
    short* fW1b  = (short*)take(H_ * E_ * 2);
    short* encb  = (short*)take((size_t)B_ * T_ * E_ * 2);

    SetupPrm sp;
    sp.enc = enc_f; sp.fhist = fhist; sp.ff = ff; sp.hidden = hidden; sp.cell = cell;
    sp.aW1 = aW1; sp.aW2 = aW2; sp.Wih = Wih; sp.Whh = Whh; sp.bih = bih; sp.bhh = bhh;
    sp.fW1 = fW1;
    sp.W1b = W1b; sp.W2b = W2b; sp.Wihb = Wihb; sp.Whhb = Whhb; sp.fW1b = fW1b;
    sp.encb = encb; sp.xb = xb; sp.hA = hA;
    sp.bcomb = bcomb; sp.alpha = alpha; sp.cbuf = cbuf;
    sp.bar = bar;

    k_setup<<<2048, 256, 0, stream>>>(sp);

    LoopPrm lp;
    lp.xb = xb;
    lp.W1b = W1b; lp.W2b = W2b; lp.Wihb = Wihb; lp.Whhb = Whhb; lp.fW1b = fW1b;
    lp.encb = encb;
    lp.ab1 = ab1; lp.ab2 = ab2; lp.fb1 = fb1; lp.fW2 = fW2; lp.fb2 = fb2; lp.ff = ff;
    lp.bcomb = bcomb; lp.alpha = alpha;
    lp.s1 = s1; lp.logit = logit; lp.ctxp = ctxp; lp.cbuf = cbuf;
    lp.hA = hA; lp.hB = hB;
    lp.out = out;
    lp.bar = bar;

    k_loop<<<NBLK, 256, 0, stream>>>(lp);
}